// Round 2
// baseline (203.146 us; speedup 1.0000x reference)
//
#include <hip/hip_runtime.h>
#include <cstdint>
#include <cstddef>

#define NUM_LAYERS 20
#define HID 1024
#define M_TOTAL 8192
#define BM 32
#define BK 32
#define KSTEPS (HID / BK)

typedef __attribute__((ext_vector_type(8))) short bf16x8;
typedef __attribute__((ext_vector_type(4))) float floatx4;
typedef __attribute__((ext_vector_type(4))) float f32x4;
typedef __attribute__((ext_vector_type(8))) unsigned short u16x8;

typedef __attribute__((address_space(1))) unsigned int as1_u32;
typedef __attribute__((address_space(3))) unsigned int as3_u32;

__device__ __forceinline__ unsigned short f2bf(float f) {
  union { float f; unsigned int u; } v; v.f = f;
  unsigned int r = v.u + 0x7fffu + ((v.u >> 16) & 1u);  // RNE
  return (unsigned short)(r >> 16);
}

__device__ __forceinline__ u16x8 pack8(f32x4 a, f32x4 b) {
  u16x8 o;
  o[0] = f2bf(a[0]); o[1] = f2bf(a[1]); o[2] = f2bf(a[2]); o[3] = f2bf(a[3]);
  o[4] = f2bf(b[0]); o[5] = f2bf(b[1]); o[6] = f2bf(b[2]); o[7] = f2bf(b[3]);
  return o;
}

// async global->LDS, 16B/lane; LDS ptr must be wave-uniform base (HW adds lane*16)
__device__ __forceinline__ void load16_lds(const void* g, void* l) {
  __builtin_amdgcn_global_load_lds(
      reinterpret_cast<as1_u32*>(reinterpret_cast<uintptr_t>(g)),
      reinterpret_cast<as3_u32*>(reinterpret_cast<uintptr_t>(l)),
      16, 0, 0);
}

// ---- Kernel 1: conv_w 20-layer sum -> bf16 wb [N=1024][K=1024].
// 40 float4 NT loads in flight per thread (MLP-bound fix from earlier rounds).
__global__ __launch_bounds__(256, 1) void wsum_kernel(const float* __restrict__ w,
                                                      unsigned short* __restrict__ wb) {
  const int P = blockIdx.x * 256 + threadIdx.x;  // ushort8 output index
  const f32x4* p = reinterpret_cast<const f32x4*>(w);
  f32x4 va[NUM_LAYERS], vb[NUM_LAYERS];
#pragma unroll
  for (int l = 0; l < NUM_LAYERS; ++l) {
    const f32x4* pl = p + (size_t)l * (HID * HID / 4) + (size_t)2 * P;
    va[l] = __builtin_nontemporal_load(pl);
    vb[l] = __builtin_nontemporal_load(pl + 1);
  }
  f32x4 s0 = va[0], s1 = vb[0];
#pragma unroll
  for (int l = 1; l < NUM_LAYERS; ++l) { s0 += va[l]; s1 += vb[l]; }
  reinterpret_cast<u16x8*>(wb)[P] = pack8(s0, s1);
}

// ---- Kernel 2: fused GEMM + RMSNorm. Full-row blocks: BM=32 rows x BN=1024 cols.
// 512 threads = 8 waves (1x8), wave tile 32x128 (2x8 frags of 16x16x32 bf16 MFMA).
// A read directly from fp32 x (reg-staged cvt), B streamed from L2-resident wb via
// global_load_lds. C never hits DRAM: row ssq reduced in-register + 1KB LDS, fp32 out.
// LDS swizzle: byte ^= ((row&6)<<3) -> 16-lane column reads are 2-way (free);
// applied on the global SOURCE of global_load_lds (linear dest) and on ds_read
// (both-sides-or-neither, rule #21).
__global__ __launch_bounds__(512, 2) void gemm_norm_kernel(const float* __restrict__ x,
                                                           const unsigned short* __restrict__ wb,
                                                           const float* __restrict__ nw,
                                                           float* __restrict__ out) {
  __shared__ unsigned short lB[2][HID * BK];  // 2 x 64 KiB
  __shared__ unsigned short lA[2][BM * BK];   // 2 x 2 KiB
  __shared__ float lred[8][32];               // cross-wave row-ssq partials

  const int tid = threadIdx.x;
  const int lane = tid & 63;
  const int w = tid >> 6;       // wave 0..7 -> N columns w*128..w*128+127
  const int quad = lane >> 4;   // 0..3
  const int mrow = lane & 15;
  const int m0 = blockIdx.x * BM;

  // --- B staging addressing: 8 issues/thread, issue i covers rows i*128 + tid/4.
  // Linear LDS byte p = i*8192 + tid*16 -> row = p>>6, phys slot = p&63.
  // Stored content pre-swizzled at the SOURCE: logical kbyte = phys ^ ((row&6)<<3).
  const int srow = tid >> 2;                          // 0..127 within row-group
  const int sphys = (tid & 3) * 16;                   // physical 16B slot in 64B row
  const int ssw = (sphys ^ ((srow & 6) << 3)) >> 1;   // swizzled k-elem offset (0..31)
  const unsigned short* gB = wb + (size_t)srow * HID + ssw;

  // --- A staging (tid<256): row=tid>>3, 4 fp32 -> 4 bf16, swizzled ds_write_b64.
  const int arow = tid >> 3;  // 0..31
  const int akq = tid & 7;
  const int adst = (arow * 64 + ((akq * 8) ^ ((arow & 6) << 3))) >> 1;  // ushort idx

  // --- fragment read offset within a 64B row (ushorts), same swizzle key
  const int rslotu = ((quad * 16) ^ ((mrow & 6) << 3)) >> 1;

  floatx4 acc[2][8] = {};

  auto stage = [&](int buf, int k0) {
    unsigned short* dB = &lB[buf][0] + w * 512;  // wave-uniform dest base
#pragma unroll
    for (int i = 0; i < 8; ++i)
      load16_lds(gB + (size_t)i * 128 * HID + k0, dB + i * 4096);
    if (tid < 256) {
      f32x4 av = __builtin_nontemporal_load(
          reinterpret_cast<const f32x4*>(x + (size_t)(m0 + arow) * HID + k0 + akq * 4));
      unsigned long long pk = (unsigned long long)f2bf(av[0]) |
                              ((unsigned long long)f2bf(av[1]) << 16) |
                              ((unsigned long long)f2bf(av[2]) << 32) |
                              ((unsigned long long)f2bf(av[3]) << 48);
      *reinterpret_cast<unsigned long long*>(&lA[buf][0] + adst) = pk;
    }
  };

  stage(0, 0);
  __syncthreads();

  // 2-phase double-buffered K loop (L2-BW-bound on B stream; stage issued early
  // so the 64KB/step B fetch overlaps ds_read+MFMA; barrier drains it).
  for (int t = 0; t < KSTEPS; ++t) {
    const int cur = t & 1;
    if (t + 1 < KSTEPS) stage(cur ^ 1, (t + 1) * BK);

    bf16x8 af[2], bfr[8];
#pragma unroll
    for (int i = 0; i < 2; ++i)
      af[i] = *reinterpret_cast<const bf16x8*>(&lA[cur][0] + (i * 16 + mrow) * 32 + rslotu);
#pragma unroll
    for (int j = 0; j < 8; ++j)
      bfr[j] = *reinterpret_cast<const bf16x8*>(&lB[cur][0] + (w * 128 + j * 16 + mrow) * 32 + rslotu);
#pragma unroll
    for (int i = 0; i < 2; ++i)
#pragma unroll
      for (int j = 0; j < 8; ++j)
        acc[i][j] = __builtin_amdgcn_mfma_f32_16x16x32_bf16(af[i], bfr[j], acc[i][j], 0, 0, 0);
    __syncthreads();
  }

  // --- fused RMSNorm epilogue. C/D layout: col=lane&15, row=quad*4+reg.
  // Per-lane partial ssq over this wave's 8 col-frags, reduce across the 16 lanes
  // sharing a quad (xor bits 0..3), then cross-wave via lred.
  float ps[2][4];
#pragma unroll
  for (int i = 0; i < 2; ++i)
#pragma unroll
    for (int r = 0; r < 4; ++r) {
      float s = 0.f;
#pragma unroll
      for (int j = 0; j < 8; ++j) { float v = acc[i][j][r]; s += v * v; }
#pragma unroll
      for (int off = 1; off < 16; off <<= 1) s += __shfl_xor(s, off, 64);
      ps[i][r] = s;
    }
  if (mrow == 0) {
#pragma unroll
    for (int i = 0; i < 2; ++i)
#pragma unroll
      for (int r = 0; r < 4; ++r)
        lred[w][i * 16 + quad * 4 + r] = ps[i][r];
  }
  __syncthreads();

  // scale = sqrt(H) * rsqrt(sum C^2 + 400*eps*H); /20 folded in (C is raw dot)
  float scale[2][4];
#pragma unroll
  for (int i = 0; i < 2; ++i)
#pragma unroll
    for (int r = 0; r < 4; ++r) {
      float s = 0.f;
#pragma unroll
      for (int ww = 0; ww < 8; ++ww) s += lred[ww][i * 16 + quad * 4 + r];
      scale[i][r] = 32.0f * rsqrtf(s + 0.4096f);  // 0.4096 = eps*H*400
    }

  float nwv[8];
#pragma unroll
  for (int j = 0; j < 8; ++j) nwv[j] = nw[w * 128 + j * 16 + mrow];

#pragma unroll
  for (int i = 0; i < 2; ++i)
#pragma unroll
    for (int r = 0; r < 4; ++r) {
      float* orow = out + (size_t)(m0 + i * 16 + quad * 4 + r) * HID + w * 128 + mrow;
      const float sc = scale[i][r];
#pragma unroll
      for (int j = 0; j < 8; ++j)
        __builtin_nontemporal_store(acc[i][j][r] * sc * nwv[j], orow + j * 16);
    }
}

extern "C" void kernel_launch(void* const* d_in, const int* in_sizes, int n_in,
                              void* d_out, int out_size, void* d_ws, size_t ws_size,
                              hipStream_t stream) {
  const float* x = (const float*)d_in[0];       // [2,4096,1024] fp32
  const float* conv_w = (const float*)d_in[1];  // [20,1024,1024] fp32
  const float* norm_w = (const float*)d_in[2];  // [1024] fp32
  float* out = (float*)d_out;                   // [2,4096,1024] fp32

  unsigned short* wb = (unsigned short*)d_ws;   // 2 MiB: summed W bf16 [N][K]

  wsum_kernel<<<512, 256, 0, stream>>>(conv_w, wb);
  gemm_norm_kernel<<<M_TOTAL / BM, 512, 0, stream>>>(x, wb, norm_w, out);
}